// Round 11
// baseline (348.783 us; speedup 1.0000x reference)
//
#include <hip/hip_runtime.h>
#include <cstdint>

#define IW 512
#define IH 512
#define NPIX (IW * IH)
#define TILE 16
#define TXN (IW / TILE)          // 32 tiles per row
#define TYN (IH / TILE)          // 32 tiles per col
#define NTILES (TXN * TYN)       // 1024
#define SEGS 8
#define NCNT (NTILES * SEGS)     // 8192
#define RECS_BYTE_OFF 131072     // records start at 128 KB into d_ws
#define EMPTY_KEY 0xFFFFFFFFFFFFFFFFull
#define BIGPID_U64 0xFFFFFFFFull

// ---------------- frozen numerics (absmax 0.0 in rounds 8/9/10) -----------
// XLA-on-gfx950 graph mirror: a*rcp(b) divisions, fmaf(dx,dx,dy*dy) coverage,
// everything else singly-rounded under contract(off).
__device__ __forceinline__ bool project_voxel(
        float x, float y, float z0,
        const float* __restrict__ m1, const float* __restrict__ m2,
        float& px, float& py, float& vz) {
#pragma clang fp contract(off)
    float vh0 = ((x * m1[0]  + y * m1[4])  + z0 * m1[8])  + m1[12];
    float vh1 = ((x * m1[1]  + y * m1[5])  + z0 * m1[9])  + m1[13];
    float vh2 = ((x * m1[2]  + y * m1[6])  + z0 * m1[10]) + m1[14];
    float vh3 = ((x * m1[3]  + y * m1[7])  + z0 * m1[11]) + m1[15];

    float wv  = (fabsf(vh3) > 1e-8f) ? vh3 : 1.0f;
    float rwv = __builtin_amdgcn_rcpf(wv);
    float vx  = vh0 * rwv;
    float vy  = vh1 * rwv;
    vz        = vh2 * rwv;

    float cl0 = ((vx * m2[0] + vy * m2[4]) + vz * m2[8])  + m2[12];
    float cl1 = ((vx * m2[1] + vy * m2[5]) + vz * m2[9])  + m2[13];
    float cl3 = ((vx * m2[3] + vy * m2[7]) + vz * m2[11]) + m2[15];

    if (!(fabsf(cl3) > 1e-8f)) return false;
    if (!(vz > 1e-6f)) return false;

    float rw   = __builtin_amdgcn_rcpf(cl3);
    float ndcx = cl0 * rw;
    float ndcy = cl1 * rw;
    px = ((ndcx + 1.0f) * 0.5f) * (float)IW;
    py = ((ndcy + 1.0f) * 0.5f) * (float)IH;
    return true;
}

// ======================= BINNED PATH =======================
// ws layout (u32): cnt[NCNT] seg-major | cur[NCNT] seg-major | off[NCNT+1]
// records (uint4 = px,py,zbits,n) at byte offset RECS_BYTE_OFF.

__global__ void zero_hdr(unsigned* __restrict__ ws) {
    int i = blockIdx.x * blockDim.x + threadIdx.x;
    if (i < 2 * NCNT) ws[i] = 0;   // cnt + cur
}

// PHASE 0: count records per (tile, seg).  PHASE 1: write records.
template <int PHASE>
__global__ __launch_bounds__(256) void bin_pass(
        const float* __restrict__ vox, const float* __restrict__ m1,
        const float* __restrict__ m2, unsigned* __restrict__ ws,
        uint4* __restrict__ recs, unsigned cap_recs, int N) {
#pragma clang fp contract(off)
    int n = blockIdx.x * blockDim.x + threadIdx.x;
    if (n >= N) return;

    float x  = vox[n * 6 + 0];
    float y  = vox[n * 6 + 1];
    float z0 = vox[n * 6 + 2];

    float px, py, vz;
    if (!project_voxel(x, y, z0, m1, m2, px, py, vz)) return;

    float fx = floorf(px);
    float fy = floorf(py);
    if (!(fx >= -1.0f && fx <= (float)IW && fy >= -1.0f && fy <= (float)IH))
        return;

    int ifx = (int)fx, ify = (int)fy;               // exact, fx,fy in [-1,512]
    int x0 = max(0, ifx - 1), x1 = min(IW - 1, ifx + 1);
    int y0 = max(0, ify - 1), y1 = min(IH - 1, ify + 1);
    if (x0 > x1 || y0 > y1) return;

    int tx0 = x0 >> 4, tx1 = x1 >> 4;
    int ty0 = y0 >> 4, ty1 = y1 >> 4;
    unsigned s = (unsigned)blockIdx.x & (SEGS - 1);

    unsigned* cnt = ws;
    unsigned* cur = ws + NCNT;
    unsigned* off = ws + 2 * NCNT;

    for (int ty = ty0; ty <= ty1; ++ty) {
        for (int tx = tx0; tx <= tx1; ++tx) {
            unsigned t = (unsigned)(ty * TXN + tx);
            if (PHASE == 0) {
                atomicAdd(&cnt[s * NTILES + t], 1u);
            } else {
                unsigned pos = atomicAdd(&cur[s * NTILES + t], 1u);
                unsigned idx = off[t * SEGS + s] + pos;
                if (idx < cap_recs) {
                    uint4 r;
                    r.x = __float_as_uint(px);
                    r.y = __float_as_uint(py);
                    r.z = __float_as_uint(vz);
                    r.w = (unsigned)n;
                    recs[idx] = r;
                }
            }
        }
    }
}

// Exclusive prefix-sum over j=0..NCNT-1 where val(j) = cnt[(j%SEGS)*NTILES + j/SEGS]
// (so records end up grouped by tile, segments contiguous within a tile).
__global__ __launch_bounds__(1024) void scan_hdr(unsigned* __restrict__ ws) {
    __shared__ unsigned ls[1024];
    unsigned* cnt = ws;
    unsigned* off = ws + 2 * NCNT;
    int tid = threadIdx.x;

    unsigned v[8];
    unsigned partial = 0;
    for (int i = 0; i < 8; ++i) {
        int j = tid * 8 + i;
        v[i] = cnt[(j & (SEGS - 1)) * NTILES + (j / SEGS)];
        partial += v[i];
    }
    ls[tid] = partial;
    __syncthreads();
    for (int st = 1; st < 1024; st <<= 1) {
        unsigned add = (tid >= st) ? ls[tid - st] : 0u;
        __syncthreads();
        ls[tid] += add;
        __syncthreads();
    }
    unsigned base = (tid > 0) ? ls[tid - 1] : 0u;
    for (int i = 0; i < 8; ++i) {
        off[tid * 8 + i] = base;
        base += v[i];
    }
    if (tid == 1023) off[NCNT] = base;   // total
}

// One workgroup per 16x16 tile: LDS z-buffer, LDS atomicMin (order-invariant
// => bit-exact), then resolve features and write d_out directly.
__global__ __launch_bounds__(256) void raster_tiles(
        const uint4* __restrict__ recs, const unsigned* __restrict__ ws,
        const float* __restrict__ vox, float* __restrict__ out,
        unsigned cap_recs) {
#pragma clang fp contract(off)
    __shared__ unsigned long long kb[TILE * TILE];
    int t  = blockIdx.x;
    int tx = t & (TXN - 1);
    int ty = t >> 5;
    int tid = threadIdx.x;

    kb[tid] = EMPTY_KEY;
    __syncthreads();

    const unsigned* off = ws + 2 * NCNT;
    unsigned start = min(off[t * SEGS], cap_recs);
    unsigned end   = min(off[t * SEGS + SEGS], cap_recs);

    int bx = tx * TILE, by = ty * TILE;

    for (unsigned i = start + tid; i < end; i += 256) {
        uint4 r = recs[i];
        float px = __uint_as_float(r.x);
        float py = __uint_as_float(r.y);
        unsigned long long zkey = ((unsigned long long)r.z) << 32;
        unsigned basepid = r.w * 9u;

        float fx = floorf(px);
        float fy = floorf(py);
        int ifx = (int)fx, ify = (int)fy;

        for (int k = 0; k < 9; ++k) {
            int ox = k % 3 - 1, oy = k / 3 - 1;
            int ix = ifx + ox, iy = ify + oy;
            if (ix < bx || ix >= bx + TILE || iy < by || iy >= by + TILE)
                continue;                              // outside this tile
            // (tile bounds imply inside-image)
            float ixf = fx + (float)ox;
            float iyf = fy + (float)oy;
            float dx = (ixf + 0.5f) - px;
            float dy = (iyf + 0.5f) - py;
            float r2 = fmaf(dx, dx, dy * dy);          // frozen form
            if (!(r2 <= 1.0f)) continue;
            unsigned long long key = zkey | (unsigned long long)(basepid + (unsigned)k);
            atomicMin(&kb[(iy - by) * TILE + (ix - bx)], key);
        }
    }
    __syncthreads();

    unsigned long long key = kb[tid];
    int ix = bx + (tid & (TILE - 1));
    int iy = by + (tid >> 4);
    float r = 0.0f, g = 0.0f, b = 0.0f;
    if (key != EMPTY_KEY) {
        unsigned n = (unsigned)(key & BIGPID_U64) / 9u;
        r = vox[n * 6 + 3];
        g = vox[n * 6 + 4];
        b = vox[n * 6 + 5];
    }
    int p = iy * IW + ix;
    out[p * 3 + 0] = r;
    out[p * 3 + 1] = g;
    out[p * 3 + 2] = b;
}

// ======================= FALLBACK PATH (round-10, proven) ==================
__global__ void init_bufs(unsigned long long* __restrict__ kb) {
    int i = blockIdx.x * blockDim.x + threadIdx.x;
    if (i < NPIX) kb[i] = EMPTY_KEY;
}

__global__ __launch_bounds__(256) void splat(
        const float* __restrict__ vox, const float* __restrict__ m1,
        const float* __restrict__ m2, unsigned long long* __restrict__ kb,
        int N) {
#pragma clang fp contract(off)
    int n = blockIdx.x * blockDim.x + threadIdx.x;
    if (n >= N) return;
    float px, py, vz;
    if (!project_voxel(vox[n*6], vox[n*6+1], vox[n*6+2], m1, m2, px, py, vz)) return;
    float fx = floorf(px), fy = floorf(py);
    if (!(fx >= -1.0f && fx <= (float)IW && fy >= -1.0f && fy <= (float)IH)) return;
    unsigned long long zhi = ((unsigned long long)__float_as_uint(vz)) << 32;
    unsigned basepid = (unsigned)n * 9u;
    for (int oy = -1; oy <= 1; ++oy)
        for (int ox = -1; ox <= 1; ++ox) {
            float ixf = fx + (float)ox, iyf = fy + (float)oy;
            if (!(ixf >= 0.0f && ixf < (float)IW && iyf >= 0.0f && iyf < (float)IH)) continue;
            float dx = (ixf + 0.5f) - px, dy = (iyf + 0.5f) - py;
            float r2 = fmaf(dx, dx, dy * dy);
            if (!(r2 <= 1.0f)) continue;
            int pix = (int)iyf * IW + (int)ixf;
            unsigned long long key = zhi | (unsigned long long)(basepid + (unsigned)((oy+1)*3+(ox+1)));
            if (key < kb[pix]) atomicMin(&kb[pix], key);
        }
}

__global__ void resolve(const unsigned long long* __restrict__ kb,
                        const float* __restrict__ vox, float* __restrict__ out) {
    int p = blockIdx.x * blockDim.x + threadIdx.x;
    if (p >= NPIX) return;
    unsigned long long key = kb[p];
    float r = 0.0f, g = 0.0f, b = 0.0f;
    if (key != EMPTY_KEY) {
        unsigned n = (unsigned)(key & BIGPID_U64) / 9u;
        r = vox[n*6+3]; g = vox[n*6+4]; b = vox[n*6+5];
    }
    out[p*3+0] = r; out[p*3+1] = g; out[p*3+2] = b;
}

// ======================= launcher =======================
extern "C" void kernel_launch(void* const* d_in, const int* in_sizes, int n_in,
                              void* d_out, int out_size, void* d_ws, size_t ws_size,
                              hipStream_t stream) {
    const float* vox = (const float*)d_in[0];
    const float* m1  = (const float*)d_in[1];
    const float* m2  = (const float*)d_in[2];
    float* out = (float*)d_out;
    int N = in_sizes[0] / 6;

    // records needed: ~1.27 * valid voxels; guard with 1.5x + slack
    size_t need = RECS_BYTE_OFF + 16ull * ((size_t)N + (size_t)N / 2 + 65536);
    if (ws_size >= need) {
        unsigned* ws = (unsigned*)d_ws;
        uint4* recs = (uint4*)((char*)d_ws + RECS_BYTE_OFF);
        unsigned cap_recs = (unsigned)((ws_size - RECS_BYTE_OFF) / 16);
        int blocks = (N + 255) / 256;

        zero_hdr<<<(2 * NCNT + 255) / 256, 256, 0, stream>>>(ws);
        bin_pass<0><<<blocks, 256, 0, stream>>>(vox, m1, m2, ws, recs, cap_recs, N);
        scan_hdr<<<1, 1024, 0, stream>>>(ws);
        bin_pass<1><<<blocks, 256, 0, stream>>>(vox, m1, m2, ws, recs, cap_recs, N);
        raster_tiles<<<NTILES, 256, 0, stream>>>(recs, ws, vox, out, cap_recs);
    } else {
        // proven fallback (round 10): needs only 2 MB of ws
        unsigned long long* kb = (unsigned long long*)d_ws;
        init_bufs<<<(NPIX + 255) / 256, 256, 0, stream>>>(kb);
        splat<<<(N + 255) / 256, 256, 0, stream>>>(vox, m1, m2, kb, N);
        resolve<<<(NPIX + 255) / 256, 256, 0, stream>>>(kb, vox, out);
    }
}

// Round 12
// 169.260 us; speedup vs baseline: 2.0606x; 2.0606x over previous
//
#include <hip/hip_runtime.h>

#define IW 512
#define IH 512
#define NPIX (IW * IH)
#define EMPTY_KEY 0xFFFFFFFFFFFFFFFFull

__global__ void init_bufs(unsigned long long* __restrict__ kb) {
    int i = blockIdx.x * blockDim.x + threadIdx.x;
    if (i < NPIX) kb[i] = EMPTY_KEY;
}

// f32 mirror of the XLA-on-gfx950 compiled reference graph (FROZEN — passed
// absmax 0.0 in rounds 8/9/10/11):
//  - divisions lowered as a * v_rcp_f32(b)
//  - r2 contracted as fma(dx,dx, dy*dy)
//  - all other ops singly-rounded (contract(off)); matmul terms exact.
__device__ __forceinline__ bool project_voxel(
        float x, float y, float z0,
        const float* __restrict__ m1, const float* __restrict__ m2,
        float& px, float& py, float& vz) {
#pragma clang fp contract(off)
    float vh0 = ((x * m1[0]  + y * m1[4])  + z0 * m1[8])  + m1[12];
    float vh1 = ((x * m1[1]  + y * m1[5])  + z0 * m1[9])  + m1[13];
    float vh2 = ((x * m1[2]  + y * m1[6])  + z0 * m1[10]) + m1[14];
    float vh3 = ((x * m1[3]  + y * m1[7])  + z0 * m1[11]) + m1[15];

    float wv  = (fabsf(vh3) > 1e-8f) ? vh3 : 1.0f;
    float rwv = __builtin_amdgcn_rcpf(wv);
    float vx  = vh0 * rwv;
    float vy  = vh1 * rwv;
    vz        = vh2 * rwv;

    float cl0 = ((vx * m2[0] + vy * m2[4]) + vz * m2[8])  + m2[12];
    float cl1 = ((vx * m2[1] + vy * m2[5]) + vz * m2[9])  + m2[13];
    float cl3 = ((vx * m2[3] + vy * m2[7]) + vz * m2[11]) + m2[15];

    if (!(fabsf(cl3) > 1e-8f)) return false;  // valid: |w| > 1e-8 (rejects NaN)
    if (!(vz > 1e-6f)) return false;          // valid: z > 1e-6  (rejects NaN)

    float rw   = __builtin_amdgcn_rcpf(cl3);
    float ndcx = cl0 * rw;
    float ndcy = cl1 * rw;
    px = ((ndcx + 1.0f) * 0.5f) * (float)IW;
    py = ((ndcy + 1.0f) * 0.5f) * (float)IH;
    return true;
}

// Single-pass splat over voxel range [n0, n1): lexicographic min over packed
// (zbits<<32 | pid).  Launched TWICE: phase A (small prefix) converges kb to
// ~final mins; phase B (the rest) then sees a quasi-stable kb, so its
// pre-check loads L2-hit instead of thrashing on atomic invalidations
// (round-9 PMC: 124 MB of kb re-fetch when all 2M voxels race at once).
__global__ __launch_bounds__(256) void splat(
        const float* __restrict__ vox, const float* __restrict__ m1,
        const float* __restrict__ m2, unsigned long long* __restrict__ kb,
        int n0, int n1) {
#pragma clang fp contract(off)
    int n = n0 + blockIdx.x * blockDim.x + threadIdx.x;
    if (n >= n1) return;

    float x  = vox[n * 6 + 0];
    float y  = vox[n * 6 + 1];
    float z0 = vox[n * 6 + 2];

    float px, py, vz;
    if (!project_voxel(x, y, z0, m1, m2, px, py, vz)) return;

    float fx = floorf(px);
    float fy = floorf(py);
    if (!(fx >= -1.0f && fx <= (float)IW && fy >= -1.0f && fy <= (float)IH))
        return;

    unsigned long long zhi = ((unsigned long long)__float_as_uint(vz)) << 32;
    unsigned basepid = (unsigned)n * 9u;

    for (int oy = -1; oy <= 1; ++oy) {
        for (int ox = -1; ox <= 1; ++ox) {
            float ixf = fx + (float)ox;
            float iyf = fy + (float)oy;
            if (!(ixf >= 0.0f && ixf < (float)IW &&
                  iyf >= 0.0f && iyf < (float)IH)) continue;
            float dx = (ixf + 0.5f) - px;
            float dy = (iyf + 0.5f) - py;
            float r2 = fmaf(dx, dx, dy * dy);   // frozen contraction form
            if (!(r2 <= 1.0f)) continue;
            int pix = (int)iyf * IW + (int)ixf;
            unsigned pid = basepid + (unsigned)((oy + 1) * 3 + (ox + 1));
            unsigned long long key = zhi | (unsigned long long)pid;
            if (key < kb[pix])                  // conservative pre-check
                atomicMin(&kb[pix], key);
        }
    }
}

__global__ void resolve(const unsigned long long* __restrict__ kb,
                        const float* __restrict__ vox,
                        float* __restrict__ out) {
    int p = blockIdx.x * blockDim.x + threadIdx.x;
    if (p >= NPIX) return;
    unsigned long long key = __builtin_nontemporal_load(kb + p);
    float r = 0.0f, g = 0.0f, b = 0.0f;
    if (key != EMPTY_KEY) {
        unsigned pid = (unsigned)(key & 0xFFFFFFFFull);
        unsigned n = pid / 9u;
        r = vox[n * 6 + 3];
        g = vox[n * 6 + 4];
        b = vox[n * 6 + 5];
    }
    out[p * 3 + 0] = r;
    out[p * 3 + 1] = g;
    out[p * 3 + 2] = b;
}

extern "C" void kernel_launch(void* const* d_in, const int* in_sizes, int n_in,
                              void* d_out, int out_size, void* d_ws, size_t ws_size,
                              hipStream_t stream) {
    const float* vox = (const float*)d_in[0];
    const float* m1  = (const float*)d_in[1];
    const float* m2  = (const float*)d_in[2];
    float* out = (float*)d_out;
    int N = in_sizes[0] / 6;

    unsigned long long* kb = (unsigned long long*)d_ws;   // 2 MB

    init_bufs<<<(NPIX + 255) / 256, 256, 0, stream>>>(kb);

    // Phase A: first 1/8 of voxels — converges kb to ~final per-pixel mins.
    int nA = N / 8;
    if (nA > 0)
        splat<<<(nA + 255) / 256, 256, 0, stream>>>(vox, m1, m2, kb, 0, nA);
    // Phase B: the rest — pre-checks against a quasi-stable kb (L2-resident).
    if (N - nA > 0)
        splat<<<((N - nA) + 255) / 256, 256, 0, stream>>>(vox, m1, m2, kb, nA, N);

    resolve<<<(NPIX + 255) / 256, 256, 0, stream>>>(kb, vox, out);
}

// Round 13
// 109.256 us; speedup vs baseline: 3.1923x; 1.5492x over previous
//
#include <hip/hip_runtime.h>

#define IW 512
#define IH 512
#define NPIX (IW * IH)
#define EMPTY_KEY 0xFFFFFFFFFFFFFFFFull

__global__ void init_bufs(unsigned long long* __restrict__ kb) {
    int i = blockIdx.x * blockDim.x + threadIdx.x;
    if (i < NPIX) kb[i] = EMPTY_KEY;
}

__global__ void snap_copy(const unsigned long long* __restrict__ kb,
                          unsigned long long* __restrict__ snap) {
    int i = blockIdx.x * blockDim.x + threadIdx.x;
    if (i < NPIX) snap[i] = kb[i];
}

// f32 mirror of the XLA-on-gfx950 compiled reference graph (FROZEN — passed
// absmax 0.0 in rounds 8-12):
//  - divisions lowered as a * v_rcp_f32(b)
//  - r2 contracted as fma(dx,dx, dy*dy)
//  - all other ops singly-rounded (contract(off)); matmul terms exact.
__device__ __forceinline__ bool project_voxel(
        float x, float y, float z0,
        const float* __restrict__ m1, const float* __restrict__ m2,
        float& px, float& py, float& vz) {
#pragma clang fp contract(off)
    float vh0 = ((x * m1[0]  + y * m1[4])  + z0 * m1[8])  + m1[12];
    float vh1 = ((x * m1[1]  + y * m1[5])  + z0 * m1[9])  + m1[13];
    float vh2 = ((x * m1[2]  + y * m1[6])  + z0 * m1[10]) + m1[14];
    float vh3 = ((x * m1[3]  + y * m1[7])  + z0 * m1[11]) + m1[15];

    float wv  = (fabsf(vh3) > 1e-8f) ? vh3 : 1.0f;
    float rwv = __builtin_amdgcn_rcpf(wv);
    float vx  = vh0 * rwv;
    float vy  = vh1 * rwv;
    vz        = vh2 * rwv;

    float cl0 = ((vx * m2[0] + vy * m2[4]) + vz * m2[8])  + m2[12];
    float cl1 = ((vx * m2[1] + vy * m2[5]) + vz * m2[9])  + m2[13];
    float cl3 = ((vx * m2[3] + vy * m2[7]) + vz * m2[11]) + m2[15];

    if (!(fabsf(cl3) > 1e-8f)) return false;  // valid: |w| > 1e-8 (rejects NaN)
    if (!(vz > 1e-6f)) return false;          // valid: z > 1e-6  (rejects NaN)

    float rw   = __builtin_amdgcn_rcpf(cl3);
    float ndcx = cl0 * rw;
    float ndcy = cl1 * rw;
    px = ((ndcx + 1.0f) * 0.5f) * (float)IW;
    py = ((ndcy + 1.0f) * 0.5f) * (float)IH;
    return true;
}

// Lexicographic min over packed (zbits<<32 | pid), two decoupled phases:
//  SNAP=0 (phase A, small prefix): BLIND atomicMin — pure write side, no
//         scattered loads on mutating lines.
//  SNAP=1 (phase B, the rest): pre-check against the READ-ONLY snapshot of
//         kb taken after phase A (lines never invalidated -> L2-resident),
//         then blind atomicMin on the live kb. Safe because keys only
//         decrease: key >= snap[pix] >= kb_final[pix] -> skip can't lose.
template <int SNAP>
__global__ __launch_bounds__(256) void splat(
        const float* __restrict__ vox, const float* __restrict__ m1,
        const float* __restrict__ m2,
        const unsigned long long* __restrict__ snap,
        unsigned long long* __restrict__ kb,
        int n0, int n1) {
#pragma clang fp contract(off)
    int n = n0 + blockIdx.x * blockDim.x + threadIdx.x;
    if (n >= n1) return;

    float x  = vox[n * 6 + 0];
    float y  = vox[n * 6 + 1];
    float z0 = vox[n * 6 + 2];

    float px, py, vz;
    if (!project_voxel(x, y, z0, m1, m2, px, py, vz)) return;

    float fx = floorf(px);
    float fy = floorf(py);
    if (!(fx >= -1.0f && fx <= (float)IW && fy >= -1.0f && fy <= (float)IH))
        return;

    unsigned long long zhi = ((unsigned long long)__float_as_uint(vz)) << 32;
    unsigned basepid = (unsigned)n * 9u;

    for (int oy = -1; oy <= 1; ++oy) {
        for (int ox = -1; ox <= 1; ++ox) {
            float ixf = fx + (float)ox;
            float iyf = fy + (float)oy;
            if (!(ixf >= 0.0f && ixf < (float)IW &&
                  iyf >= 0.0f && iyf < (float)IH)) continue;
            float dx = (ixf + 0.5f) - px;
            float dy = (iyf + 0.5f) - py;
            float r2 = fmaf(dx, dx, dy * dy);   // frozen contraction form
            if (!(r2 <= 1.0f)) continue;
            int pix = (int)iyf * IW + (int)ixf;
            unsigned pid = basepid + (unsigned)((oy + 1) * 3 + (ox + 1));
            unsigned long long key = zhi | (unsigned long long)pid;
            if (SNAP) {
                if (key < snap[pix])            // read-only, L2-resident
                    atomicMin(&kb[pix], key);   // blind — no live-line load
            } else {
                atomicMin(&kb[pix], key);       // blind
            }
        }
    }
}

__global__ void resolve(const unsigned long long* __restrict__ kb,
                        const float* __restrict__ vox,
                        float* __restrict__ out) {
    int p = blockIdx.x * blockDim.x + threadIdx.x;
    if (p >= NPIX) return;
    unsigned long long key = kb[p];
    float r = 0.0f, g = 0.0f, b = 0.0f;
    if (key != EMPTY_KEY) {
        unsigned pid = (unsigned)(key & 0xFFFFFFFFull);
        unsigned n = pid / 9u;
        r = vox[n * 6 + 3];
        g = vox[n * 6 + 4];
        b = vox[n * 6 + 5];
    }
    out[p * 3 + 0] = r;
    out[p * 3 + 1] = g;
    out[p * 3 + 2] = b;
}

extern "C" void kernel_launch(void* const* d_in, const int* in_sizes, int n_in,
                              void* d_out, int out_size, void* d_ws, size_t ws_size,
                              hipStream_t stream) {
    const float* vox = (const float*)d_in[0];
    const float* m1  = (const float*)d_in[1];
    const float* m2  = (const float*)d_in[2];
    float* out = (float*)d_out;
    int N = in_sizes[0] / 6;

    unsigned long long* kb   = (unsigned long long*)d_ws;          // 2 MB
    unsigned long long* snap = kb + NPIX;                          // 2 MB

    const int pixblocks = (NPIX + 255) / 256;
    init_bufs<<<pixblocks, 256, 0, stream>>>(kb);

    if (ws_size >= 2ull * NPIX * sizeof(unsigned long long)) {
        int nA = N / 8;
        // Phase A: blind atomics, converges kb to ~final mins.
        splat<0><<<(nA + 255) / 256, 256, 0, stream>>>(vox, m1, m2, nullptr, kb, 0, nA);
        // Freeze a snapshot for the read side.
        snap_copy<<<pixblocks, 256, 0, stream>>>(kb, snap);
        // Phase B: pre-check vs snapshot (read-only), blind atomic on kb.
        splat<1><<<((N - nA) + 255) / 256, 256, 0, stream>>>(vox, m1, m2, snap, kb, nA, N);
    } else {
        // minimal-ws fallback: single blind pass (round-8 style, proven)
        splat<0><<<(N + 255) / 256, 256, 0, stream>>>(vox, m1, m2, nullptr, kb, 0, N);
    }

    resolve<<<pixblocks, 256, 0, stream>>>(kb, vox, out);
}